// Round 9
// baseline (372.319 us; speedup 1.0000x reference)
//
#include <hip/hip_runtime.h>
#include <math.h>

// TokenChoiceTopKRouter, round 9: k2 ring-prefetch + plane-major partials.
//
// R8 evidence: k2 VGPR=128 (pa[16]/pb[16] = 128 regs of prefetch) -> pipeline
// serialized, x at 2.8 TB/s; WRITE 189 MB vs 33.5 ideal (partial-line RMW on
// [t][e] partials). Fix 1: depth-3 ring (4 slots, statically indexed) = 32
// prefetch VGPRs, 48 KB/CU in flight. Fix 2: wsP -> [plane=ks*64+e][token]:
// full-line writes in k2, lane-coalesced reads in k3.
//
// Pipeline: pack_w -> k2 (K-split MFMA GEMM, B-slice in LDS, partials) ->
// k3 (reduce + sigmoid + top-8 + LDS hist) -> k5 (hist reduce, no atomics).

constexpr int DIM = 4096;
constexpr int NE  = 64;
constexpr size_t WSB_BYTES = 1048576;            // packed B stream (1 MB)

typedef __attribute__((ext_vector_type(8))) short bf16x8;
typedef __attribute__((ext_vector_type(4))) float f32x4;

// ---------- k1: pack w into per-K-slice hi/lo B-fragment stream ----------
// 16B-unit u = ks*8192 + sl*512 + f*64 + lane, f = et*2 + hl.
// Content: e = et*16 + (lane&15), k = ks*512 + sl*32 + 8*(lane>>4) (+j).
__global__ void pack_w(const float* __restrict__ w, ushort* __restrict__ wsB) {
  const int u  = blockIdx.x * 256 + threadIdx.x;   // 65536 units
  const int l  = u & 63;
  const int f  = (u >> 6) & 7;
  const int sl = (u >> 9) & 15;
  const int ks = u >> 13;
  const int et = f >> 1, hl = f & 1;
  const int e  = et * 16 + (l & 15);
  const int k  = ks * 512 + sl * 32 + 8 * (l >> 4);
  const float* src = w + (size_t)e * DIM + k;
  ushort v[8];
#pragma unroll
  for (int j = 0; j < 8; ++j) {
    float xv = src[j];
    unsigned xb = __float_as_uint(xv);
    unsigned hb = xb & 0xffff0000u;                // exact hi (truncation)
    if (hl == 0) {
      v[j] = (ushort)(hb >> 16);
    } else {
      float lf = xv - __uint_as_float(hb);
      unsigned lb = __float_as_uint(lf);
      lb = lb + 0x7fffu + ((lb >> 16) & 1u);       // RNE to bf16
      v[j] = (ushort)(lb >> 16);
    }
  }
  ushort* d = wsB + (size_t)u * 8;
#pragma unroll
  for (int j = 0; j < 8; ++j) d[j] = v[j];
}

// ---------- shared helper: f32x8 -> hi/lo bf16x8 ----------
__device__ __forceinline__ void split8(const float4& a0, const float4& a1,
                                       bf16x8& ahi, bf16x8& alo) {
  float av[8] = {a0.x, a0.y, a0.z, a0.w, a1.x, a1.y, a1.z, a1.w};
#pragma unroll
  for (int j = 0; j < 8; ++j) {
    unsigned xb = __float_as_uint(av[j]);
    unsigned hb = xb & 0xffff0000u;
    float lf = av[j] - __uint_as_float(hb);
    unsigned lb = __float_as_uint(lf);
    lb = lb + 0x7fffu + ((lb >> 16) & 1u);
    ahi[j] = (short)(hb >> 16);
    alo[j] = (short)(lb >> 16);
  }
}

// ---------- k2: K-split MFMA GEMM, B in LDS, ring-prefetched x ----------
__global__ __launch_bounds__(512, 1)
void router_k2(const float* __restrict__ x, const uint4* __restrict__ wsB,
               float* __restrict__ wsP, int ntok) {
  __shared__ uint4 ldsB[8192];                    // 128 KB B-slice
  const int tid  = threadIdx.x;
  const int ks   = blockIdx.x & 7;                // == XCD id (L2-local B)
  const int tg   = blockIdx.x >> 3;
  const int wave = tid >> 6;
  const int lane = tid & 63;
  const int col  = lane & 15;                     // token col / expert col
  const int kq   = lane >> 4;                     // k-quad

  // stage B-slice once (coalesced global, linear LDS)
  const uint4* src = wsB + (size_t)ks * 8192;
#pragma unroll
  for (int it = 0; it < 16; ++it) ldsB[it * 512 + tid] = src[it * 512 + tid];
  __syncthreads();

  const bf16x8* B16 = (const bf16x8*)ldsB;
  const int t0w = tg * 512 + wave * 64;

#pragma unroll 1
  for (int tile = 0; tile < 4; ++tile) {
    const int t0 = t0w + tile * 16;
    const float* xr = x + (size_t)(t0 + col) * DIM + ks * 512 + 8 * kq;

    f32x4 acc[4];
#pragma unroll
    for (int et = 0; et < 4; ++et) acc[et] = (f32x4){0.f, 0.f, 0.f, 0.f};

    // depth-3 register ring (4 slots, statically indexed under full unroll)
    float4 ra[4], rb[4];
#pragma unroll
    for (int s = 0; s < 3; ++s) {
      ra[s] = *(const float4*)(xr + s * 32);
      rb[s] = *(const float4*)(xr + s * 32 + 4);
    }

#pragma unroll
    for (int s = 0; s < 16; ++s) {
      const int cur = s & 3;
      const int nxt = (s + 3) & 3;
      if (s + 3 < 16) {
        ra[nxt] = *(const float4*)(xr + (s + 3) * 32);
        rb[nxt] = *(const float4*)(xr + (s + 3) * 32 + 4);
      }
      bf16x8 ahi, alo;
      split8(ra[cur], rb[cur], ahi, alo);
#pragma unroll
      for (int et = 0; et < 4; ++et) {
        bf16x8 bh = B16[(s * 8 + et * 2 + 0) * 64 + lane];
        bf16x8 bl = B16[(s * 8 + et * 2 + 1) * 64 + lane];
        acc[et] = __builtin_amdgcn_mfma_f32_16x16x32_bf16(ahi, bh, acc[et], 0, 0, 0);
        acc[et] = __builtin_amdgcn_mfma_f32_16x16x32_bf16(alo, bh, acc[et], 0, 0, 0);
        acc[et] = __builtin_amdgcn_mfma_f32_16x16x32_bf16(ahi, bl, acc[et], 0, 0, 0);
      }
    }

    // partials, plane-major: wsP[(ks*64 + e)*ntok + t]. Per wave, the 4-tile
    // loop fills tokens t0w..t0w+63 of each plane -> full-line L2 merges.
    // D layout (m89-verified): e-col = et*16+col, token-row = 4*kq+r.
#pragma unroll
    for (int et = 0; et < 4; ++et)
#pragma unroll
      for (int r = 0; r < 4; ++r)
        wsP[(size_t)(ks * 64 + et * 16 + col) * ntok + t0 + 4 * kq + r] = acc[et][r];
  }
}

// ---------- k3: reduce K-slices + sigmoid + top-8 + LDS histogram ----------
__global__ __launch_bounds__(128, 1)
void router_k3(const float* __restrict__ wsP, const float* __restrict__ bias,
               float* __restrict__ out_scores, float* __restrict__ out_idx,
               float* __restrict__ wsH, int ntok) {
  __shared__ float hist[NE];
  if (threadIdx.x < NE) hist[threadIdx.x] = 0.f;
  __syncthreads();

  const int t = blockIdx.x * 128 + threadIdx.x;   // lane-consecutive tokens
  float a[64];
#pragma unroll
  for (int e = 0; e < NE; ++e) a[e] = wsP[(size_t)e * ntok + t];
#pragma unroll
  for (int ks = 1; ks < 8; ++ks)
#pragma unroll
    for (int e = 0; e < NE; ++e)
      a[e] += wsP[(size_t)(ks * 64 + e) * ntok + t];

  float key[8], sv[8];
  int   idx[8];
#pragma unroll
  for (int j = 0; j < 8; ++j) { key[j] = -1e30f; sv[j] = 0.f; idx[j] = 0; }

#pragma unroll
  for (int e = 0; e < NE; ++e) {
    float s = 1.0f / (1.0f + expf(-a[e]));
    float k = s + bias[e];
    // bubble-insert; strict > keeps lower index on ties (lax.top_k order)
    float ck = k, cv = s; int ci = e;
#pragma unroll
    for (int j = 0; j < 8; ++j) {
      bool g = ck > key[j];
      float tk = key[j], tv = sv[j]; int ti = idx[j];
      key[j] = g ? ck : tk; sv[j] = g ? cv : tv; idx[j] = g ? ci : ti;
      ck = g ? tk : ck;     cv = g ? tv : cv;    ci = g ? ti : ci;
    }
  }

  float sum = 1e-20f;
#pragma unroll
  for (int j = 0; j < 8; ++j) sum += sv[j];
  float inv = 1.0f / sum;
#pragma unroll
  for (int j = 0; j < 8; ++j) {
    out_scores[t * 8 + j] = sv[j] * inv;
    out_idx[t * 8 + j]    = (float)idx[j];
    atomicAdd(&hist[idx[j]], 1.0f);       // LDS atomic: 64 bins, cheap
  }
  __syncthreads();
  if (threadIdx.x < NE) wsH[(size_t)blockIdx.x * NE + threadIdx.x] = hist[threadIdx.x];
}

// ---------- k5: reduce per-block histograms -> counts (no atomics) ----------
__global__ __launch_bounds__(64)
void router_k5(const float* __restrict__ wsH, float* __restrict__ counts,
               int nblk) {
  const int e = threadIdx.x;              // 0..63
  float s = 0.f;
  for (int b = 0; b < nblk; ++b) s += wsH[(size_t)b * NE + e];
  counts[e] = s;
}

// ---------- R6 proven mid-fallback (ws >= 1 MB): direct B-stream MFMA ------
__global__ __launch_bounds__(512, 2)
void router_mfma(const float* __restrict__ x, const ushort* __restrict__ ws,
                 const float* __restrict__ bias,
                 float* __restrict__ out_scores, float* __restrict__ out_idx,
                 float* __restrict__ counts) {
  __shared__ float logits[64 * 64];
  const int tid  = threadIdx.x;
  const int lane = tid & 63;
  const int wv   = tid >> 6;
  const int wt   = wv & 3;
  const int wk   = wv >> 2;
  const int tok0 = blockIdx.x * 64;
  const int col  = lane & 15;
  const int kq   = lane >> 4;
  const float* xrow = x + (size_t)(tok0 + wt * 16 + col) * DIM + wk * 2048 + 8 * kq;
  const ushort* wsl = ws + (size_t)lane * 8;
  f32x4 acc[4];
#pragma unroll
  for (int et = 0; et < 4; ++et) acc[et] = (f32x4){0.f, 0.f, 0.f, 0.f};
  const int s0 = wk * 64;
  float4 a0c = *(const float4*)(xrow + 0);
  float4 a1c = *(const float4*)(xrow + 4);
  bf16x8 bc[8];
#pragma unroll
  for (int f = 0; f < 8; ++f)
    bc[f] = *(const bf16x8*)(wsl + (size_t)(s0 * 8 + f) * 64 * 8);
#pragma unroll 1
  for (int ls = 0; ls < 64; ls += 2) {
    const int so = s0 + ls + 1;
    float4 a0o = *(const float4*)(xrow + (ls + 1) * 32);
    float4 a1o = *(const float4*)(xrow + (ls + 1) * 32 + 4);
    bf16x8 bo[8];
#pragma unroll
    for (int f = 0; f < 8; ++f)
      bo[f] = *(const bf16x8*)(wsl + (size_t)(so * 8 + f) * 64 * 8);
    {
      bf16x8 ahi, alo;
      split8(a0c, a1c, ahi, alo);
#pragma unroll
      for (int et = 0; et < 4; ++et) {
        acc[et] = __builtin_amdgcn_mfma_f32_16x16x32_bf16(ahi, bc[et * 2 + 0], acc[et], 0, 0, 0);
        acc[et] = __builtin_amdgcn_mfma_f32_16x16x32_bf16(alo, bc[et * 2 + 0], acc[et], 0, 0, 0);
        acc[et] = __builtin_amdgcn_mfma_f32_16x16x32_bf16(ahi, bc[et * 2 + 1], acc[et], 0, 0, 0);
      }
    }
    if (ls + 2 < 64) {
      const int se = s0 + ls + 2;
      a0c = *(const float4*)(xrow + (ls + 2) * 32);
      a1c = *(const float4*)(xrow + (ls + 2) * 32 + 4);
#pragma unroll
      for (int f = 0; f < 8; ++f)
        bc[f] = *(const bf16x8*)(wsl + (size_t)(se * 8 + f) * 64 * 8);
    }
    {
      bf16x8 ahi, alo;
      split8(a0o, a1o, ahi, alo);
#pragma unroll
      for (int et = 0; et < 4; ++et) {
        acc[et] = __builtin_amdgcn_mfma_f32_16x16x32_bf16(ahi, bo[et * 2 + 0], acc[et], 0, 0, 0);
        acc[et] = __builtin_amdgcn_mfma_f32_16x16x32_bf16(alo, bo[et * 2 + 0], acc[et], 0, 0, 0);
        acc[et] = __builtin_amdgcn_mfma_f32_16x16x32_bf16(ahi, bo[et * 2 + 1], acc[et], 0, 0, 0);
      }
    }
  }
  if (wk == 0) {
#pragma unroll
    for (int et = 0; et < 4; ++et)
#pragma unroll
      for (int r = 0; r < 4; ++r) {
        int t = wt * 16 + 4 * kq + r;
        int e = et * 16 + col;
        logits[t * 64 + ((e + t) & 63)] = acc[et][r];
      }
  }
  __syncthreads();
  if (wk == 1) {
#pragma unroll
    for (int et = 0; et < 4; ++et)
#pragma unroll
      for (int r = 0; r < 4; ++r) {
        int t = wt * 16 + 4 * kq + r;
        int e = et * 16 + col;
        logits[t * 64 + ((e + t) & 63)] += acc[et][r];
      }
  }
  __syncthreads();
  if (tid < 64) {
    const int t = tid, gt = tok0 + t;
    float key[8], sv[8]; int idx[8];
#pragma unroll
    for (int j = 0; j < 8; ++j) { key[j] = -1e30f; sv[j] = 0.f; idx[j] = 0; }
    for (int e = 0; e < NE; ++e) {
      float l = logits[t * 64 + ((e + t) & 63)];
      float s = 1.0f / (1.0f + expf(-l));
      float k = s + bias[e];
      float ck = k, cv = s; int ci = e;
#pragma unroll
      for (int j = 0; j < 8; ++j) {
        bool g = ck > key[j];
        float tk = key[j], tv = sv[j]; int ti = idx[j];
        key[j] = g ? ck : tk; sv[j] = g ? cv : tv; idx[j] = g ? ci : ti;
        ck = g ? tk : ck;     cv = g ? tv : cv;    ci = g ? ti : ci;
      }
    }
    float sum = 1e-20f;
#pragma unroll
    for (int j = 0; j < 8; ++j) sum += sv[j];
    float inv = 1.0f / sum;
#pragma unroll
    for (int j = 0; j < 8; ++j) {
      out_scores[gt * 8 + j] = sv[j] * inv;
      out_idx[gt * 8 + j]    = (float)idx[j];
      atomicAdd(&counts[idx[j]], 1.0f);
    }
  }
}

// ---------- R5 proven last-resort fallback (fp32 scalar-w) ----------
constexpr int KSTEP = 32;
constexpr int FNSTEP = DIM / KSTEP;
constexpr int ROWF4 = 9;
constexpr int BUF4  = 64 * ROWF4;

__global__ __launch_bounds__(512, 2)
void router_fallback(const float* __restrict__ x, const float* __restrict__ w,
                     const float* __restrict__ bias,
                     float* __restrict__ out_scores, float* __restrict__ out_idx,
                     float* __restrict__ counts) {
  __shared__ float4 lds4[2 * BUF4];
  float* ldsf = (float*)lds4;
  const int tid  = threadIdx.x;
  const int lane = tid & 63;
  const int eg   = __builtin_amdgcn_readfirstlane(tid >> 6);
  const int tok0 = blockIdx.x * 64;
  const int r0 = tid >> 3, j0 = tid & 7;
  const float* gp = &x[(size_t)(tok0 + r0) * DIM + j0 * 4];
  const int l0 = r0 * ROWF4 + j0;
  float acc[8];
#pragma unroll
  for (int e = 0; e < 8; ++e) acc[e] = 0.f;
  lds4[l0] = *(const float4*)gp;
  __syncthreads();
  const float* wbase = w + (size_t)eg * 8 * DIM;
#pragma unroll 1
  for (int c = 0; c < FNSTEP; ++c) {
    float4 pf;
    if (c + 1 < FNSTEP) pf = *(const float4*)(gp + (c + 1) * KSTEP);
    float xr[KSTEP];
    {
      const float4* xrow = lds4 + (c & 1) * BUF4 + lane * ROWF4;
#pragma unroll
      for (int i = 0; i < 8; ++i) {
        float4 q = xrow[i];
        xr[4 * i + 0] = q.x; xr[4 * i + 1] = q.y;
        xr[4 * i + 2] = q.z; xr[4 * i + 3] = q.w;
      }
    }
#pragma unroll
    for (int e = 0; e < 8; ++e) {
      const float* wr = wbase + e * DIM + c * KSTEP;
#pragma unroll
      for (int k = 0; k < KSTEP; ++k) acc[e] = fmaf(xr[k], wr[k], acc[e]);
    }
    if (c + 1 < FNSTEP) lds4[((c + 1) & 1) * BUF4 + l0] = pf;
    __syncthreads();
  }
#pragma unroll
  for (int j = 0; j < 8; ++j) {
    int e = eg * 8 + j;
    ldsf[lane * 64 + ((e + lane) & 63)] = acc[j];
  }
  __syncthreads();
  if (tid < 64) {
    const int t = tid, gt = tok0 + t;
    float key[8], sv[8]; int idx[8];
#pragma unroll
    for (int j = 0; j < 8; ++j) { key[j] = -1e30f; sv[j] = 0.f; idx[j] = 0; }
    for (int e = 0; e < NE; ++e) {
      float l = ldsf[t * 64 + ((e + t) & 63)];
      float s = 1.0f / (1.0f + expf(-l));
      float k = s + bias[e];
      float ck = k, cv = s; int ci = e;
#pragma unroll
      for (int j = 0; j < 8; ++j) {
        bool g = ck > key[j];
        float tk = key[j], tv = sv[j]; int ti = idx[j];
        key[j] = g ? ck : tk; sv[j] = g ? cv : tv; idx[j] = g ? ci : ti;
        ck = g ? tk : ck;     cv = g ? tv : cv;    ci = g ? ti : ci;
      }
    }
    float sum = 1e-20f;
#pragma unroll
    for (int j = 0; j < 8; ++j) sum += sv[j];
    float inv = 1.0f / sum;
#pragma unroll
    for (int j = 0; j < 8; ++j) {
      out_scores[gt * 8 + j] = sv[j] * inv;
      out_idx[gt * 8 + j]    = (float)idx[j];
      atomicAdd(&counts[idx[j]], 1.0f);
    }
  }
}

extern "C" void kernel_launch(void* const* d_in, const int* in_sizes, int n_in,
                              void* d_out, int out_size, void* d_ws, size_t ws_size,
                              hipStream_t stream) {
  const float* x    = (const float*)d_in[0];
  const float* w    = (const float*)d_in[1];
  const float* bias = (const float*)d_in[2];

  const int ntok = in_sizes[0] / DIM;              // 16384
  float* out        = (float*)d_out;
  float* out_scores = out;
  float* out_idx    = out + ntok * 8;
  float* counts     = out + 2 * ntok * 8;

  hipMemsetAsync(counts, 0, NE * sizeof(float), stream);

  const int    nblk3     = ntok / 128;
  const size_t wsp_bytes = (size_t)8 * ntok * 64 * sizeof(float);   // 32 MB
  const size_t wsh_bytes = (size_t)nblk3 * NE * sizeof(float);      // 32 KB
  const size_t need = WSB_BYTES + wsp_bytes + wsh_bytes;

  if (ws_size >= need && (ntok % 512) == 0) {
    ushort* wsB = (ushort*)d_ws;
    float*  wsP = (float*)((char*)d_ws + WSB_BYTES);
    float*  wsH = (float*)((char*)d_ws + WSB_BYTES + wsp_bytes);
    hipLaunchKernelGGL(pack_w, dim3(256), dim3(256), 0, stream, w, wsB);
    hipLaunchKernelGGL(router_k2, dim3(8 * (ntok / 512)), dim3(512), 0, stream,
                       x, (const uint4*)wsB, wsP, ntok);
    hipLaunchKernelGGL(router_k3, dim3(nblk3), dim3(128), 0, stream,
                       wsP, bias, out_scores, out_idx, wsH, ntok);
    hipLaunchKernelGGL(router_k5, dim3(1), dim3(64), 0, stream,
                       wsH, counts, nblk3);
  } else if (ws_size >= WSB_BYTES) {
    ushort* wsB = (ushort*)d_ws;
    hipLaunchKernelGGL(pack_w, dim3(256), dim3(256), 0, stream, w, wsB);
    hipLaunchKernelGGL(router_mfma, dim3(ntok / 64), dim3(512), 0, stream,
                       x, wsB, bias, out_scores, out_idx, counts);
  } else {
    hipLaunchKernelGGL(router_fallback, dim3(ntok / 64), dim3(512), 0, stream,
                       x, w, bias, out_scores, out_idx, counts);
  }
}

// Round 10
// 150.345 us; speedup vs baseline: 2.4764x; 2.4764x over previous
//
#include <hip/hip_runtime.h>
#include <math.h>

// TokenChoiceTopKRouter, round 10: fully-fused, global_load_lds staging.
//
// R8/R9 evidence: WRITE ~190 MB unchanged across a total wsP-layout change +
// VGPR pinned at 128 -> the write amplification is VGPR-staging spill, not
// partials RMW. Structural fix: stage x and packed-B HBM/L2 -> LDS via
// __builtin_amdgcn_global_load_lds (width 16) -- zero staging registers.
// Fused full-K per block (no wsP, no k3): block = 64 tokens x 64 experts,
// 64 chunks of 64k, x-tile 16KB + B-chunk 16KB per chunk, double-buffered,
// one __syncthreads per chunk (m97 structure). Per-lane state ~55 VGPR.
// Epilogue: rotated-logits cross-wave k-half reduce + sigmoid + biased top-8
// + normalize (proven) + LDS hist -> wsH -> k5 (no global atomics).

constexpr int DIM = 4096;
constexpr int NE  = 64;
constexpr size_t WSB_BYTES = 1048576;            // packed B stream (1 MB)

typedef __attribute__((ext_vector_type(8))) short bf16x8;
typedef __attribute__((ext_vector_type(4))) float f32x4;

#define GLD16(gp, lp)                                                        \
  __builtin_amdgcn_global_load_lds(                                          \
      (const __attribute__((address_space(1))) unsigned int*)(gp),           \
      (__attribute__((address_space(3))) unsigned int*)(lp), 16, 0, 0)

// ---------- k1: pack w into hi/lo B-fragment stream (R6/R9-proven) ----------
// 16B-unit u = sl*512 + f*64 + lane  (sl = 0..127 global 32k-step, f=et*2+hl)
// Content: e = et*16 + (lane&15), k = sl*32 + 8*(lane>>4) (+j), hi/lo bf16.
__global__ void pack_w(const float* __restrict__ w, ushort* __restrict__ wsB) {
  const int u  = blockIdx.x * 256 + threadIdx.x;   // 65536 units
  const int l  = u & 63;
  const int f  = (u >> 6) & 7;
  const int sl = u >> 9;                           // 0..127
  const int et = f >> 1, hl = f & 1;
  const int e  = et * 16 + (l & 15);
  const int k  = sl * 32 + 8 * (l >> 4);
  const float* src = w + (size_t)e * DIM + k;
  ushort v[8];
#pragma unroll
  for (int j = 0; j < 8; ++j) {
    float xv = src[j];
    unsigned xb = __float_as_uint(xv);
    unsigned hb = xb & 0xffff0000u;                // exact hi (truncation)
    if (hl == 0) {
      v[j] = (ushort)(hb >> 16);
    } else {
      float lf = xv - __uint_as_float(hb);
      unsigned lb = __float_as_uint(lf);
      lb = lb + 0x7fffu + ((lb >> 16) & 1u);       // RNE to bf16
      v[j] = (ushort)(lb >> 16);
    }
  }
  ushort* d = wsB + (size_t)u * 8;
#pragma unroll
  for (int j = 0; j < 8; ++j) d[j] = v[j];
}

// ---------- shared helper: f32x8 -> hi/lo bf16x8 ----------
__device__ __forceinline__ void split8(const float4& a0, const float4& a1,
                                       bf16x8& ahi, bf16x8& alo) {
  float av[8] = {a0.x, a0.y, a0.z, a0.w, a1.x, a1.y, a1.z, a1.w};
#pragma unroll
  for (int j = 0; j < 8; ++j) {
    unsigned xb = __float_as_uint(av[j]);
    unsigned hb = xb & 0xffff0000u;
    float lf = av[j] - __uint_as_float(hb);
    unsigned lb = __float_as_uint(lf);
    lb = lb + 0x7fffu + ((lb >> 16) & 1u);
    ahi[j] = (short)(hb >> 16);
    alo[j] = (short)(lb >> 16);
  }
}

// ---------- fused main kernel ----------
// LDS map (bytes): buf b in {0,1}: x at b*32768 (64 rows x 256B),
// B at b*32768+16384 ([sl-within-chunk][f][lane] linear, 16KB).
// Epilogue reuse: logits f32[64][64] at 0, hist f32[64] at 16384.
__global__ __launch_bounds__(512, 2)
void router_fused(const float* __restrict__ x, const char* __restrict__ wsB,
                  const float* __restrict__ bias,
                  float* __restrict__ out_scores, float* __restrict__ out_idx,
                  float* __restrict__ wsH) {
  __shared__ char lds[65536];
  const int tid  = threadIdx.x;
  const int wv   = tid >> 6;
  const int lane = tid & 63;
  const int wt   = wv & 3;            // token tile 0..3
  const int wk   = wv >> 2;           // k half 0..1
  const int col  = lane & 15;
  const int kq   = lane >> 4;
  const int tok0 = blockIdx.x * 64;

  // staging geometry: x rows tr(+32), 16 lanes x 16B per row; B linear.
  const int tr    = tid >> 4;         // 0..31
  const int kslot = tid & 15;

  f32x4 acc[4];
#pragma unroll
  for (int et = 0; et < 4; ++et) acc[et] = (f32x4){0.f, 0.f, 0.f, 0.f};

  // prologue: stage chunk 0 into buf 0
  {
    const float* gx0 = x + (size_t)(tok0 + tr) * DIM + kslot * 4;
    const float* gx1 = x + (size_t)(tok0 + 32 + tr) * DIM + kslot * 4;
    char* lx = lds;
    GLD16(gx0, lx + tr * 256 + kslot * 16);
    GLD16(gx1, lx + 8192 + tr * 256 + kslot * 16);
    const char* gb = wsB + (size_t)tid * 16;
    char* lb = lds + 16384;
    GLD16(gb, lb + tid * 16);
    GLD16(gb + 8192, lb + 8192 + tid * 16);
  }

#pragma unroll 1
  for (int c = 0; c < 64; ++c) {
    __syncthreads();   // compiler drains vmcnt: chunk c staged & visible

    // stage chunk c+1 into the other buffer (DMA, no registers)
    if (c + 1 < 64) {
      const int b1 = (c + 1) & 1;
      const float* gx0 = x + (size_t)(tok0 + tr) * DIM + (c + 1) * 64 + kslot * 4;
      const float* gx1 = x + (size_t)(tok0 + 32 + tr) * DIM + (c + 1) * 64 + kslot * 4;
      char* lx = lds + b1 * 32768;
      GLD16(gx0, lx + tr * 256 + kslot * 16);
      GLD16(gx1, lx + 8192 + tr * 256 + kslot * 16);
      const char* gb = wsB + ((size_t)(2 * (c + 1)) * 512 + tid) * 16;
      char* lb = lds + b1 * 32768 + 16384;
      GLD16(gb, lb + tid * 16);
      GLD16(gb + 8192, lb + 8192 + tid * 16);
    }

    // compute chunk c from buf c&1
    const int b = c & 1;
    const char* lx = lds + b * 32768;
    const char* lb = lds + b * 32768 + 16384 + wk * 8192;  // this wave's 32k step
    // A frag: token row wt*16+col, k_local = wk*32 + kq*8 + j  (R6-proven map)
    const float4* ap =
        (const float4*)(lx + (wt * 16 + col) * 256 + wk * 128 + kq * 32);
    bf16x8 ahi, alo;
    split8(ap[0], ap[1], ahi, alo);
    const bf16x8* bp = (const bf16x8*)lb;
#pragma unroll
    for (int et = 0; et < 4; ++et) {
      bf16x8 bh = bp[(et * 2 + 0) * 64 + lane];
      bf16x8 bl = bp[(et * 2 + 1) * 64 + lane];
      acc[et] = __builtin_amdgcn_mfma_f32_16x16x32_bf16(ahi, bh, acc[et], 0, 0, 0);
      acc[et] = __builtin_amdgcn_mfma_f32_16x16x32_bf16(alo, bh, acc[et], 0, 0, 0);
      acc[et] = __builtin_amdgcn_mfma_f32_16x16x32_bf16(ahi, bl, acc[et], 0, 0, 0);
    }
  }

  // ---- epilogue: cross-wave k-half reduce in rotated logits ----
  __syncthreads();                         // all compute done; LDS reusable
  float* logits = (float*)lds;             // 16 KB
  float* hist   = (float*)(lds + 16384);   // 256 B
  if (tid < 64) hist[tid] = 0.f;
  // D layout (m89/R6-verified): e-col = et*16+col, token-row = 4*kq+r
  if (wk == 0) {
#pragma unroll
    for (int et = 0; et < 4; ++et)
#pragma unroll
      for (int r = 0; r < 4; ++r) {
        int t = wt * 16 + 4 * kq + r;
        int e = et * 16 + col;
        logits[t * 64 + ((e + t) & 63)] = acc[et][r];
      }
  }
  __syncthreads();
  if (wk == 1) {
#pragma unroll
    for (int et = 0; et < 4; ++et)
#pragma unroll
      for (int r = 0; r < 4; ++r) {
        int t = wt * 16 + 4 * kq + r;
        int e = et * 16 + col;
        logits[t * 64 + ((e + t) & 63)] += acc[et][r];
      }
  }
  __syncthreads();

  // ---- sigmoid + biased top-8 + normalize + LDS hist (proven tail) ----
  if (tid < 64) {
    const int t = tid, gt = tok0 + t;
    float key[8], sv[8];
    int   idx[8];
#pragma unroll
    for (int j = 0; j < 8; ++j) { key[j] = -1e30f; sv[j] = 0.f; idx[j] = 0; }

    for (int e = 0; e < NE; ++e) {
      float l = logits[t * 64 + ((e + t) & 63)];
      float s = 1.0f / (1.0f + expf(-l));
      float k = s + bias[e];
      // bubble-insert; strict > keeps lower index on ties (lax.top_k order)
      float ck = k, cv = s; int ci = e;
#pragma unroll
      for (int j = 0; j < 8; ++j) {
        bool g = ck > key[j];
        float tk = key[j], tv = sv[j]; int ti = idx[j];
        key[j] = g ? ck : tk; sv[j] = g ? cv : tv; idx[j] = g ? ci : ti;
        ck = g ? tk : ck;     cv = g ? tv : cv;    ci = g ? ti : ci;
      }
    }

    float sum = 1e-20f;
#pragma unroll
    for (int j = 0; j < 8; ++j) sum += sv[j];
    float inv = 1.0f / sum;
#pragma unroll
    for (int j = 0; j < 8; ++j) {
      out_scores[gt * 8 + j] = sv[j] * inv;
      out_idx[gt * 8 + j]    = (float)idx[j];
      atomicAdd(&hist[idx[j]], 1.0f);      // LDS atomic, wave-local
    }
    wsH[(size_t)blockIdx.x * NE + tid] = hist[tid];
  }
}

// ---------- k5: reduce per-block histograms -> counts (no atomics) ----------
__global__ __launch_bounds__(64)
void router_k5(const float* __restrict__ wsH, float* __restrict__ counts,
               int nblk) {
  const int e = threadIdx.x;              // 0..63
  float s = 0.f;
  for (int b = 0; b < nblk; ++b) s += wsH[(size_t)b * NE + e];
  counts[e] = s;
}

// ---------- R6 proven mid-fallback (ws >= 1 MB): direct B-stream MFMA ------
__global__ __launch_bounds__(512, 2)
void router_mfma(const float* __restrict__ x, const ushort* __restrict__ ws,
                 const float* __restrict__ bias,
                 float* __restrict__ out_scores, float* __restrict__ out_idx,
                 float* __restrict__ counts) {
  __shared__ float logits[64 * 64];
  const int tid  = threadIdx.x;
  const int lane = tid & 63;
  const int wv   = tid >> 6;
  const int wt   = wv & 3;
  const int wk   = wv >> 2;
  const int tok0 = blockIdx.x * 64;
  const int col  = lane & 15;
  const int kq   = lane >> 4;
  const float* xrow = x + (size_t)(tok0 + wt * 16 + col) * DIM + wk * 2048 + 8 * kq;
  const ushort* wsl = ws + (size_t)lane * 8;
  f32x4 acc[4];
#pragma unroll
  for (int et = 0; et < 4; ++et) acc[et] = (f32x4){0.f, 0.f, 0.f, 0.f};
  const int s0 = wk * 64;
  float4 a0c = *(const float4*)(xrow + 0);
  float4 a1c = *(const float4*)(xrow + 4);
  bf16x8 bc[8];
#pragma unroll
  for (int f = 0; f < 8; ++f)
    bc[f] = *(const bf16x8*)(wsl + (size_t)(s0 * 8 + f) * 64 * 8);
#pragma unroll 1
  for (int ls = 0; ls < 64; ls += 2) {
    const int so = s0 + ls + 1;
    float4 a0o = *(const float4*)(xrow + (ls + 1) * 32);
    float4 a1o = *(const float4*)(xrow + (ls + 1) * 32 + 4);
    bf16x8 bo[8];
#pragma unroll
    for (int f = 0; f < 8; ++f)
      bo[f] = *(const bf16x8*)(wsl + (size_t)(so * 8 + f) * 64 * 8);
    {
      bf16x8 ahi, alo;
      split8(a0c, a1c, ahi, alo);
#pragma unroll
      for (int et = 0; et < 4; ++et) {
        acc[et] = __builtin_amdgcn_mfma_f32_16x16x32_bf16(ahi, bc[et * 2 + 0], acc[et], 0, 0, 0);
        acc[et] = __builtin_amdgcn_mfma_f32_16x16x32_bf16(alo, bc[et * 2 + 0], acc[et], 0, 0, 0);
        acc[et] = __builtin_amdgcn_mfma_f32_16x16x32_bf16(ahi, bc[et * 2 + 1], acc[et], 0, 0, 0);
      }
    }
    if (ls + 2 < 64) {
      const int se = s0 + ls + 2;
      a0c = *(const float4*)(xrow + (ls + 2) * 32);
      a1c = *(const float4*)(xrow + (ls + 2) * 32 + 4);
#pragma unroll
      for (int f = 0; f < 8; ++f)
        bc[f] = *(const bf16x8*)(wsl + (size_t)(se * 8 + f) * 64 * 8);
    }
    {
      bf16x8 ahi, alo;
      split8(a0o, a1o, ahi, alo);
#pragma unroll
      for (int et = 0; et < 4; ++et) {
        acc[et] = __builtin_amdgcn_mfma_f32_16x16x32_bf16(ahi, bo[et * 2 + 0], acc[et], 0, 0, 0);
        acc[et] = __builtin_amdgcn_mfma_f32_16x16x32_bf16(alo, bo[et * 2 + 0], acc[et], 0, 0, 0);
        acc[et] = __builtin_amdgcn_mfma_f32_16x16x32_bf16(ahi, bo[et * 2 + 1], acc[et], 0, 0, 0);
      }
    }
  }
  if (wk == 0) {
#pragma unroll
    for (int et = 0; et < 4; ++et)
#pragma unroll
      for (int r = 0; r < 4; ++r) {
        int t = wt * 16 + 4 * kq + r;
        int e = et * 16 + col;
        logits[t * 64 + ((e + t) & 63)] = acc[et][r];
      }
  }
  __syncthreads();
  if (wk == 1) {
#pragma unroll
    for (int et = 0; et < 4; ++et)
#pragma unroll
      for (int r = 0; r < 4; ++r) {
        int t = wt * 16 + 4 * kq + r;
        int e = et * 16 + col;
        logits[t * 64 + ((e + t) & 63)] += acc[et][r];
      }
  }
  __syncthreads();
  if (tid < 64) {
    const int t = tid, gt = tok0 + t;
    float key[8], sv[8]; int idx[8];
#pragma unroll
    for (int j = 0; j < 8; ++j) { key[j] = -1e30f; sv[j] = 0.f; idx[j] = 0; }
    for (int e = 0; e < NE; ++e) {
      float l = logits[t * 64 + ((e + t) & 63)];
      float s = 1.0f / (1.0f + expf(-l));
      float k = s + bias[e];
      float ck = k, cv = s; int ci = e;
#pragma unroll
      for (int j = 0; j < 8; ++j) {
        bool g = ck > key[j];
        float tk = key[j], tv = sv[j]; int ti = idx[j];
        key[j] = g ? ck : tk; sv[j] = g ? cv : tv; idx[j] = g ? ci : ti;
        ck = g ? tk : ck;     cv = g ? tv : cv;    ci = g ? ti : ci;
      }
    }
    float sum = 1e-20f;
#pragma unroll
    for (int j = 0; j < 8; ++j) sum += sv[j];
    float inv = 1.0f / sum;
#pragma unroll
    for (int j = 0; j < 8; ++j) {
      out_scores[gt * 8 + j] = sv[j] * inv;
      out_idx[gt * 8 + j]    = (float)idx[j];
      atomicAdd(&counts[idx[j]], 1.0f);
    }
  }
}

// ---------- R5 proven last-resort fallback (fp32 scalar-w) ----------
constexpr int KSTEP = 32;
constexpr int FNSTEP = DIM / KSTEP;
constexpr int ROWF4 = 9;
constexpr int BUF4  = 64 * ROWF4;

__global__ __launch_bounds__(512, 2)
void router_fallback(const float* __restrict__ x, const float* __restrict__ w,
                     const float* __restrict__ bias,
                     float* __restrict__ out_scores, float* __restrict__ out_idx,
                     float* __restrict__ counts) {
  __shared__ float4 lds4[2 * BUF4];
  float* ldsf = (float*)lds4;
  const int tid  = threadIdx.x;
  const int lane = tid & 63;
  const int eg   = __builtin_amdgcn_readfirstlane(tid >> 6);
  const int tok0 = blockIdx.x * 64;
  const int r0 = tid >> 3, j0 = tid & 7;
  const float* gp = &x[(size_t)(tok0 + r0) * DIM + j0 * 4];
  const int l0 = r0 * ROWF4 + j0;
  float acc[8];
#pragma unroll
  for (int e = 0; e < 8; ++e) acc[e] = 0.f;
  lds4[l0] = *(const float4*)gp;
  __syncthreads();
  const float* wbase = w + (size_t)eg * 8 * DIM;
#pragma unroll 1
  for (int c = 0; c < FNSTEP; ++c) {
    float4 pf;
    if (c + 1 < FNSTEP) pf = *(const float4*)(gp + (c + 1) * KSTEP);
    float xr[KSTEP];
    {
      const float4* xrow = lds4 + (c & 1) * BUF4 + lane * ROWF4;
#pragma unroll
      for (int i = 0; i < 8; ++i) {
        float4 q = xrow[i];
        xr[4 * i + 0] = q.x; xr[4 * i + 1] = q.y;
        xr[4 * i + 2] = q.z; xr[4 * i + 3] = q.w;
      }
    }
#pragma unroll
    for (int e = 0; e < 8; ++e) {
      const float* wr = wbase + e * DIM + c * KSTEP;
#pragma unroll
      for (int k = 0; k < KSTEP; ++k) acc[e] = fmaf(xr[k], wr[k], acc[e]);
    }
    if (c + 1 < FNSTEP) lds4[((c + 1) & 1) * BUF4 + l0] = pf;
    __syncthreads();
  }
#pragma unroll
  for (int j = 0; j < 8; ++j) {
    int e = eg * 8 + j;
    ldsf[lane * 64 + ((e + lane) & 63)] = acc[j];
  }
  __syncthreads();
  if (tid < 64) {
    const int t = tid, gt = tok0 + t;
    float key[8], sv[8]; int idx[8];
#pragma unroll
    for (int j = 0; j < 8; ++j) { key[j] = -1e30f; sv[j] = 0.f; idx[j] = 0; }
    for (int e = 0; e < NE; ++e) {
      float l = ldsf[t * 64 + ((e + t) & 63)];
      float s = 1.0f / (1.0f + expf(-l));
      float k = s + bias[e];
      float ck = k, cv = s; int ci = e;
#pragma unroll
      for (int j = 0; j < 8; ++j) {
        bool g = ck > key[j];
        float tk = key[j], tv = sv[j]; int ti = idx[j];
        key[j] = g ? ck : tk; sv[j] = g ? cv : tv; idx[j] = g ? ci : ti;
        ck = g ? tk : ck;     cv = g ? tv : cv;    ci = g ? ti : ci;
      }
    }
    float sum = 1e-20f;
#pragma unroll
    for (int j = 0; j < 8; ++j) sum += sv[j];
    float inv = 1.0f / sum;
#pragma unroll
    for (int j = 0; j < 8; ++j) {
      out_scores[gt * 8 + j] = sv[j] * inv;
      out_idx[gt * 8 + j]    = (float)idx[j];
      atomicAdd(&counts[idx[j]], 1.0f);
    }
  }
}

extern "C" void kernel_launch(void* const* d_in, const int* in_sizes, int n_in,
                              void* d_out, int out_size, void* d_ws, size_t ws_size,
                              hipStream_t stream) {
  const float* x    = (const float*)d_in[0];
  const float* w    = (const float*)d_in[1];
  const float* bias = (const float*)d_in[2];

  const int ntok = in_sizes[0] / DIM;              // 16384
  float* out        = (float*)d_out;
  float* out_scores = out;
  float* out_idx    = out + ntok * 8;
  float* counts     = out + 2 * ntok * 8;

  hipMemsetAsync(counts, 0, NE * sizeof(float), stream);

  const int    nblk      = ntok / 64;              // 256
  const size_t wsh_bytes = (size_t)nblk * NE * sizeof(float);  // 64 KB
  const size_t need = WSB_BYTES + wsh_bytes;

  if (ws_size >= need && (ntok % 64) == 0) {
    ushort* wsB = (ushort*)d_ws;
    float*  wsH = (float*)((char*)d_ws + WSB_BYTES);
    hipLaunchKernelGGL(pack_w, dim3(256), dim3(256), 0, stream, w, wsB);
    hipLaunchKernelGGL(router_fused, dim3(nblk), dim3(512), 0, stream,
                       x, (const char*)wsB, bias, out_scores, out_idx, wsH);
    hipLaunchKernelGGL(router_k5, dim3(1), dim3(64), 0, stream,
                       wsH, counts, nblk);
  } else if (ws_size >= WSB_BYTES) {
    ushort* wsB = (ushort*)d_ws;
    hipLaunchKernelGGL(pack_w, dim3(256), dim3(256), 0, stream, w, wsB);
    hipLaunchKernelGGL(router_mfma, dim3(ntok / 64), dim3(512), 0, stream,
                       x, wsB, bias, out_scores, out_idx, counts);
  } else {
    hipLaunchKernelGGL(router_fallback, dim3(ntok / 64), dim3(512), 0, stream,
                       x, w, bias, out_scores, out_idx, counts);
  }
}

// Round 11
// 138.967 us; speedup vs baseline: 2.6792x; 1.0819x over previous
//
#include <hip/hip_runtime.h>
#include <math.h>

// TokenChoiceTopKRouter, round 11: counted-vmcnt 4-buffer pipeline + swizzle.
//
// R10 (150 us): global_load_lds staging proved out (no spill), but
// __syncthreads drained vmcnt(0) per chunk (residual ~900cy HBM latency eaten
// at every barrier) and the A-read was a 16-way bank conflict (row stride
// 256B). R11: 32k chunks, 4 LDS buffers, depth-2 prefetch with
// s_waitcnt vmcnt(4) + raw s_barrier (never vmcnt(0) in-loop, T4); waves =
// 4 token-tiles x 2 expert-halves over FULL K (no cross-wave K-reduce);
// x global-source pre-swizzle (ks ^ (tr&7)) + same XOR on the A-read ->
// conflict-free (rule #21). Epilogue: rotated logits + proven top-8 tail +
// LDS hist -> wsH -> k5 (no global atomics).

constexpr int DIM = 4096;
constexpr int NE  = 64;
constexpr int NCH = 128;                         // 32k chunks
constexpr size_t WSB_BYTES = 1048576;            // packed B stream (1 MB)

typedef __attribute__((ext_vector_type(8))) short bf16x8;
typedef __attribute__((ext_vector_type(4))) float f32x4;

#define GLD16(gp, lp)                                                        \
  __builtin_amdgcn_global_load_lds(                                          \
      (const __attribute__((address_space(1))) unsigned int*)(gp),           \
      (__attribute__((address_space(3))) unsigned int*)(lp), 16, 0, 0)

// ---------- k1: pack w into hi/lo B-fragment stream (R6/R10-proven) ---------
// 16B-unit u = sl*512 + f*64 + lane (sl = 32k step 0..127, f = et*2 + hl).
// Content: e = et*16 + (lane&15), k = sl*32 + 8*(lane>>4) (+j), hi/lo bf16.
__global__ void pack_w(const float* __restrict__ w, ushort* __restrict__ wsB) {
  const int u  = blockIdx.x * 256 + threadIdx.x;   // 65536 units
  const int l  = u & 63;
  const int f  = (u >> 6) & 7;
  const int sl = u >> 9;                           // 0..127
  const int et = f >> 1, hl = f & 1;
  const int e  = et * 16 + (l & 15);
  const int k  = sl * 32 + 8 * (l >> 4);
  const float* src = w + (size_t)e * DIM + k;
  ushort v[8];
#pragma unroll
  for (int j = 0; j < 8; ++j) {
    float xv = src[j];
    unsigned xb = __float_as_uint(xv);
    unsigned hb = xb & 0xffff0000u;                // exact hi (truncation)
    if (hl == 0) {
      v[j] = (ushort)(hb >> 16);
    } else {
      float lf = xv - __uint_as_float(hb);
      unsigned lb = __float_as_uint(lf);
      lb = lb + 0x7fffu + ((lb >> 16) & 1u);       // RNE to bf16
      v[j] = (ushort)(lb >> 16);
    }
  }
  ushort* d = wsB + (size_t)u * 8;
#pragma unroll
  for (int j = 0; j < 8; ++j) d[j] = v[j];
}

// ---------- shared helper: f32x8 -> hi/lo bf16x8 ----------
__device__ __forceinline__ void split8(const float4& a0, const float4& a1,
                                       bf16x8& ahi, bf16x8& alo) {
  float av[8] = {a0.x, a0.y, a0.z, a0.w, a1.x, a1.y, a1.z, a1.w};
#pragma unroll
  for (int j = 0; j < 8; ++j) {
    unsigned xb = __float_as_uint(av[j]);
    unsigned hb = xb & 0xffff0000u;
    float lf = av[j] - __uint_as_float(hb);
    unsigned lb = __float_as_uint(lf);
    lb = lb + 0x7fffu + ((lb >> 16) & 1u);
    ahi[j] = (short)(hb >> 16);
    alo[j] = (short)(lb >> 16);
  }
}

// ---------- fused main kernel ----------
// LDS: buf q = c&3 at q*16384: x 8 KB (64 rows x 128 B, k-units src-swizzled
// by ks^(tr&7)), B 8 KB at +8192 ([f][lane] 16B units). Epilogue reuse:
// logits f32[64][64] at 0, hist f32[64] at 16384.
__global__ __launch_bounds__(512, 2)
void router_fused(const float* __restrict__ x, const char* __restrict__ wsB,
                  const float* __restrict__ bias,
                  float* __restrict__ out_scores, float* __restrict__ out_idx,
                  float* __restrict__ wsH) {
  __shared__ char lds[65536];
  const int tid  = threadIdx.x;
  const int wv   = tid >> 6;
  const int lane = tid & 63;
  const int tt   = wv & 3;            // token tile 0..3
  const int eh   = wv >> 2;           // expert half 0..1
  const int col  = lane & 15;
  const int kq   = lane >> 4;
  const int tok0 = blockIdx.x * 64;

  // staging: x row tr, 16B-unit ks; source unit pre-swizzled, LDS linear.
  const int tr = tid >> 3;            // 0..63
  const int ks = tid & 7;
  const int su = ks ^ (tr & 7);       // global k-unit this thread fetches
  const float* gxrow = x + (size_t)(tok0 + tr) * DIM + su * 4;  // + c*32
  const char*  gb    = wsB + (size_t)tid * 16;                  // + c*8192

  f32x4 acc[2];
  acc[0] = (f32x4){0.f, 0.f, 0.f, 0.f};
  acc[1] = (f32x4){0.f, 0.f, 0.f, 0.f};

#define STAGE(cc)                                                            \
  do {                                                                       \
    char* lq = lds + ((cc) & 3) * 16384;                                     \
    GLD16(gxrow + (cc) * 32, lq + tid * 16);                                 \
    GLD16(gb + (size_t)(cc) * 8192, lq + 8192 + tid * 16);                   \
  } while (0)

  STAGE(0);
  STAGE(1);

  // A-read swizzle constants for this lane (row r = tt*16+col, s = col&7)
  const int arow = tt * 16 + col;
  const int u0   = (kq * 2) ^ (col & 7);
  const int u1   = (kq * 2 + 1) ^ (col & 7);

#pragma unroll 1
  for (int c = 0; c < NCH; ++c) {
    if (c + 2 < NCH) {
      STAGE(c + 2);
      asm volatile("s_waitcnt vmcnt(4)" ::: "memory");  // c done; c+1,c+2 fly
    } else if (c + 2 == NCH) {
      asm volatile("s_waitcnt vmcnt(2)" ::: "memory");
    } else {
      asm volatile("s_waitcnt vmcnt(0)" ::: "memory");
    }
    __builtin_amdgcn_s_barrier();       // raw: no compiler vmcnt(0) drain
    __builtin_amdgcn_sched_barrier(0);  // keep ds_reads below the barrier

    const char* lq = lds + (c & 3) * 16384;
    float4 q0 = *(const float4*)(lq + arow * 128 + u0 * 16);
    float4 q1 = *(const float4*)(lq + arow * 128 + u1 * 16);
    bf16x8 ahi, alo;
    split8(q0, q1, ahi, alo);
    const char* lb = lq + 8192;
#pragma unroll
    for (int et2 = 0; et2 < 2; ++et2) {
      const int f = (eh * 2 + et2) * 2;
      bf16x8 bh = *(const bf16x8*)(lb + (f + 0) * 1024 + lane * 16);
      bf16x8 bl = *(const bf16x8*)(lb + (f + 1) * 1024 + lane * 16);
      acc[et2] = __builtin_amdgcn_mfma_f32_16x16x32_bf16(ahi, bh, acc[et2], 0, 0, 0);
      acc[et2] = __builtin_amdgcn_mfma_f32_16x16x32_bf16(alo, bh, acc[et2], 0, 0, 0);
      acc[et2] = __builtin_amdgcn_mfma_f32_16x16x32_bf16(ahi, bl, acc[et2], 0, 0, 0);
    }
  }
#undef STAGE

  // ---- epilogue: each wave owns full-K logits for 16 tok x 32 exp ----
  __syncthreads();                         // full drain; LDS reusable
  float* logits = (float*)lds;             // 16 KB
  float* hist   = (float*)(lds + 16384);   // 256 B
  if (tid < 64) hist[tid] = 0.f;
  // D layout (m89/R6-verified): e-col = et*16+col, token-row = 4*kq+r
#pragma unroll
  for (int et2 = 0; et2 < 2; ++et2)
#pragma unroll
    for (int r = 0; r < 4; ++r) {
      int t = tt * 16 + 4 * kq + r;
      int e = eh * 32 + et2 * 16 + col;
      logits[t * 64 + ((e + t) & 63)] = acc[et2][r];
    }
  __syncthreads();

  // ---- sigmoid + biased top-8 + normalize + LDS hist (proven tail) ----
  if (tid < 64) {
    const int t = tid, gt = tok0 + t;
    float key[8], sv[8];
    int   idx[8];
#pragma unroll
    for (int j = 0; j < 8; ++j) { key[j] = -1e30f; sv[j] = 0.f; idx[j] = 0; }

    for (int e = 0; e < NE; ++e) {
      float l = logits[t * 64 + ((e + t) & 63)];
      float s = 1.0f / (1.0f + expf(-l));
      float k = s + bias[e];
      // bubble-insert; strict > keeps lower index on ties (lax.top_k order)
      float ck = k, cv = s; int ci = e;
#pragma unroll
      for (int j = 0; j < 8; ++j) {
        bool g = ck > key[j];
        float tk = key[j], tv = sv[j]; int ti = idx[j];
        key[j] = g ? ck : tk; sv[j] = g ? cv : tv; idx[j] = g ? ci : ti;
        ck = g ? tk : ck;     cv = g ? tv : cv;    ci = g ? ti : ci;
      }
    }

    float sum = 1e-20f;
#pragma unroll
    for (int j = 0; j < 8; ++j) sum += sv[j];
    float inv = 1.0f / sum;
#pragma unroll
    for (int j = 0; j < 8; ++j) {
      out_scores[gt * 8 + j] = sv[j] * inv;
      out_idx[gt * 8 + j]    = (float)idx[j];
      atomicAdd(&hist[idx[j]], 1.0f);      // LDS atomic, wave-local
    }
    wsH[(size_t)blockIdx.x * NE + tid] = hist[tid];
  }
}

// ---------- k5: reduce per-block histograms -> counts (no atomics) ----------
__global__ __launch_bounds__(256)
void router_k5(const float* __restrict__ wsH, float* __restrict__ counts,
               int nblk) {
  __shared__ float part[256];
  const int e = threadIdx.x & 63, p = threadIdx.x >> 6;
  float s = 0.f;
  for (int b = p; b < nblk; b += 4) s += wsH[(size_t)b * NE + e];
  part[p * 64 + e] = s;
  __syncthreads();
  if (threadIdx.x < 64)
    counts[e] = part[e] + part[64 + e] + part[128 + e] + part[192 + e];
}

// ---------- R6 proven mid-fallback (ws >= 1 MB): direct B-stream MFMA ------
__global__ __launch_bounds__(512, 2)
void router_mfma(const float* __restrict__ x, const ushort* __restrict__ ws,
                 const float* __restrict__ bias,
                 float* __restrict__ out_scores, float* __restrict__ out_idx,
                 float* __restrict__ counts) {
  __shared__ float logits[64 * 64];
  const int tid  = threadIdx.x;
  const int lane = tid & 63;
  const int wv   = tid >> 6;
  const int wt   = wv & 3;
  const int wk   = wv >> 2;
  const int tok0 = blockIdx.x * 64;
  const int col  = lane & 15;
  const int kq   = lane >> 4;
  const float* xrow = x + (size_t)(tok0 + wt * 16 + col) * DIM + wk * 2048 + 8 * kq;
  const ushort* wsl = ws + (size_t)lane * 8;
  f32x4 acc[4];
#pragma unroll
  for (int et = 0; et < 4; ++et) acc[et] = (f32x4){0.f, 0.f, 0.f, 0.f};
  const int s0 = wk * 64;
  float4 a0c = *(const float4*)(xrow + 0);
  float4 a1c = *(const float4*)(xrow + 4);
  bf16x8 bc[8];
#pragma unroll
  for (int f = 0; f < 8; ++f)
    bc[f] = *(const bf16x8*)(wsl + (size_t)(s0 * 8 + f) * 64 * 8);
#pragma unroll 1
  for (int ls = 0; ls < 64; ls += 2) {
    const int so = s0 + ls + 1;
    float4 a0o = *(const float4*)(xrow + (ls + 1) * 32);
    float4 a1o = *(const float4*)(xrow + (ls + 1) * 32 + 4);
    bf16x8 bo[8];
#pragma unroll
    for (int f = 0; f < 8; ++f)
      bo[f] = *(const bf16x8*)(wsl + (size_t)(so * 8 + f) * 64 * 8);
    {
      bf16x8 ahi, alo;
      split8(a0c, a1c, ahi, alo);
#pragma unroll
      for (int et = 0; et < 4; ++et) {
        acc[et] = __builtin_amdgcn_mfma_f32_16x16x32_bf16(ahi, bc[et * 2 + 0], acc[et], 0, 0, 0);
        acc[et] = __builtin_amdgcn_mfma_f32_16x16x32_bf16(alo, bc[et * 2 + 0], acc[et], 0, 0, 0);
        acc[et] = __builtin_amdgcn_mfma_f32_16x16x32_bf16(ahi, bc[et * 2 + 1], acc[et], 0, 0, 0);
      }
    }
    if (ls + 2 < 64) {
      const int se = s0 + ls + 2;
      a0c = *(const float4*)(xrow + (ls + 2) * 32);
      a1c = *(const float4*)(xrow + (ls + 2) * 32 + 4);
#pragma unroll
      for (int f = 0; f < 8; ++f)
        bc[f] = *(const bf16x8*)(wsl + (size_t)(se * 8 + f) * 64 * 8);
    }
    {
      bf16x8 ahi, alo;
      split8(a0o, a1o, ahi, alo);
#pragma unroll
      for (int et = 0; et < 4; ++et) {
        acc[et] = __builtin_amdgcn_mfma_f32_16x16x32_bf16(ahi, bo[et * 2 + 0], acc[et], 0, 0, 0);
        acc[et] = __builtin_amdgcn_mfma_f32_16x16x32_bf16(alo, bo[et * 2 + 0], acc[et], 0, 0, 0);
        acc[et] = __builtin_amdgcn_mfma_f32_16x16x32_bf16(ahi, bo[et * 2 + 1], acc[et], 0, 0, 0);
      }
    }
  }
  if (wk == 0) {
#pragma unroll
    for (int et = 0; et < 4; ++et)
#pragma unroll
      for (int r = 0; r < 4; ++r) {
        int t = wt * 16 + 4 * kq + r;
        int e = et * 16 + col;
        logits[t * 64 + ((e + t) & 63)] = acc[et][r];
      }
  }
  __syncthreads();
  if (wk == 1) {
#pragma unroll
    for (int et = 0; et < 4; ++et)
#pragma unroll
      for (int r = 0; r < 4; ++r) {
        int t = wt * 16 + 4 * kq + r;
        int e = et * 16 + col;
        logits[t * 64 + ((e + t) & 63)] += acc[et][r];
      }
  }
  __syncthreads();
  if (tid < 64) {
    const int t = tid, gt = tok0 + t;
    float key[8], sv[8]; int idx[8];
#pragma unroll
    for (int j = 0; j < 8; ++j) { key[j] = -1e30f; sv[j] = 0.f; idx[j] = 0; }
    for (int e = 0; e < NE; ++e) {
      float l = logits[t * 64 + ((e + t) & 63)];
      float s = 1.0f / (1.0f + expf(-l));
      float k = s + bias[e];
      float ck = k, cv = s; int ci = e;
#pragma unroll
      for (int j = 0; j < 8; ++j) {
        bool g = ck > key[j];
        float tk = key[j], tv = sv[j]; int ti = idx[j];
        key[j] = g ? ck : tk; sv[j] = g ? cv : tv; idx[j] = g ? ci : ti;
        ck = g ? tk : ck;     cv = g ? tv : cv;    ci = g ? ti : ci;
      }
    }
    float sum = 1e-20f;
#pragma unroll
    for (int j = 0; j < 8; ++j) sum += sv[j];
    float inv = 1.0f / sum;
#pragma unroll
    for (int j = 0; j < 8; ++j) {
      out_scores[gt * 8 + j] = sv[j] * inv;
      out_idx[gt * 8 + j]    = (float)idx[j];
      atomicAdd(&counts[idx[j]], 1.0f);
    }
  }
}

// ---------- R5 proven last-resort fallback (fp32 scalar-w) ----------
constexpr int KSTEP = 32;
constexpr int FNSTEP = DIM / KSTEP;
constexpr int ROWF4 = 9;
constexpr int BUF4  = 64 * ROWF4;

__global__ __launch_bounds__(512, 2)
void router_fallback(const float* __restrict__ x, const float* __restrict__ w,
                     const float* __restrict__ bias,
                     float* __restrict__ out_scores, float* __restrict__ out_idx,
                     float* __restrict__ counts) {
  __shared__ float4 lds4[2 * BUF4];
  float* ldsf = (float*)lds4;
  const int tid  = threadIdx.x;
  const int lane = tid & 63;
  const int eg   = __builtin_amdgcn_readfirstlane(tid >> 6);
  const int tok0 = blockIdx.x * 64;
  const int r0 = tid >> 3, j0 = tid & 7;
  const float* gp = &x[(size_t)(tok0 + r0) * DIM + j0 * 4];
  const int l0 = r0 * ROWF4 + j0;
  float acc[8];
#pragma unroll
  for (int e = 0; e < 8; ++e) acc[e] = 0.f;
  lds4[l0] = *(const float4*)gp;
  __syncthreads();
  const float* wbase = w + (size_t)eg * 8 * DIM;
#pragma unroll 1
  for (int c = 0; c < FNSTEP; ++c) {
    float4 pf;
    if (c + 1 < FNSTEP) pf = *(const float4*)(gp + (c + 1) * KSTEP);
    float xr[KSTEP];
    {
      const float4* xrow = lds4 + (c & 1) * BUF4 + lane * ROWF4;
#pragma unroll
      for (int i = 0; i < 8; ++i) {
        float4 q = xrow[i];
        xr[4 * i + 0] = q.x; xr[4 * i + 1] = q.y;
        xr[4 * i + 2] = q.z; xr[4 * i + 3] = q.w;
      }
    }
#pragma unroll
    for (int e = 0; e < 8; ++e) {
      const float* wr = wbase + e * DIM + c * KSTEP;
#pragma unroll
      for (int k = 0; k < KSTEP; ++k) acc[e] = fmaf(xr[k], wr[k], acc[e]);
    }
    if (c + 1 < FNSTEP) lds4[((c + 1) & 1) * BUF4 + l0] = pf;
    __syncthreads();
  }
#pragma unroll
  for (int j = 0; j < 8; ++j) {
    int e = eg * 8 + j;
    ldsf[lane * 64 + ((e + lane) & 63)] = acc[j];
  }
  __syncthreads();
  if (tid < 64) {
    const int t = tid, gt = tok0 + t;
    float key[8], sv[8]; int idx[8];
#pragma unroll
    for (int j = 0; j < 8; ++j) { key[j] = -1e30f; sv[j] = 0.f; idx[j] = 0; }
    for (int e = 0; e < NE; ++e) {
      float l = ldsf[t * 64 + ((e + t) & 63)];
      float s = 1.0f / (1.0f + expf(-l));
      float k = s + bias[e];
      float ck = k, cv = s; int ci = e;
#pragma unroll
      for (int j = 0; j < 8; ++j) {
        bool g = ck > key[j];
        float tk = key[j], tv = sv[j]; int ti = idx[j];
        key[j] = g ? ck : tk; sv[j] = g ? cv : tv; idx[j] = g ? ci : ti;
        ck = g ? tk : ck;     cv = g ? tv : cv;    ci = g ? ti : ci;
      }
    }
    float sum = 1e-20f;
#pragma unroll
    for (int j = 0; j < 8; ++j) sum += sv[j];
    float inv = 1.0f / sum;
#pragma unroll
    for (int j = 0; j < 8; ++j) {
      out_scores[gt * 8 + j] = sv[j] * inv;
      out_idx[gt * 8 + j]    = (float)idx[j];
      atomicAdd(&counts[idx[j]], 1.0f);
    }
  }
}

extern "C" void kernel_launch(void* const* d_in, const int* in_sizes, int n_in,
                              void* d_out, int out_size, void* d_ws, size_t ws_size,
                              hipStream_t stream) {
  const float* x    = (const float*)d_in[0];
  const float* w    = (const float*)d_in[1];
  const float* bias = (const float*)d_in[2];

  const int ntok = in_sizes[0] / DIM;              // 16384
  float* out        = (float*)d_out;
  float* out_scores = out;
  float* out_idx    = out + ntok * 8;
  float* counts     = out + 2 * ntok * 8;

  hipMemsetAsync(counts, 0, NE * sizeof(float), stream);

  const int    nblk      = ntok / 64;              // 256
  const size_t wsh_bytes = (size_t)nblk * NE * sizeof(float);  // 64 KB
  const size_t need = WSB_BYTES + wsh_bytes;

  if (ws_size >= need && (ntok % 64) == 0) {
    ushort* wsB = (ushort*)d_ws;
    float*  wsH = (float*)((char*)d_ws + WSB_BYTES);
    hipLaunchKernelGGL(pack_w, dim3(256), dim3(256), 0, stream, w, wsB);
    hipLaunchKernelGGL(router_fused, dim3(nblk), dim3(512), 0, stream,
                       x, (const char*)wsB, bias, out_scores, out_idx, wsH);
    hipLaunchKernelGGL(router_k5, dim3(1), dim3(256), 0, stream,
                       wsH, counts, nblk);
  } else if (ws_size >= WSB_BYTES) {
    ushort* wsB = (ushort*)d_ws;
    hipLaunchKernelGGL(pack_w, dim3(256), dim3(256), 0, stream, w, wsB);
    hipLaunchKernelGGL(router_mfma, dim3(ntok / 64), dim3(512), 0, stream,
                       x, wsB, bias, out_scores, out_idx, counts);
  } else {
    hipLaunchKernelGGL(router_fallback, dim3(ntok / 64), dim3(512), 0, stream,
                       x, w, bias, out_scores, out_idx, counts);
  }
}